// Round 6
// baseline (868.002 us; speedup 1.0000x reference)
//
#include <hip/hip_runtime.h>

typedef unsigned short u16;
typedef unsigned int u32;
typedef float f32x4 __attribute__((ext_vector_type(4)));
typedef short bf16x8 __attribute__((ext_vector_type(8)));

#define DIM 2048
#define SEQ 2048
#define NHEAD 16
#define HDIM 128
#define BATCH 2
#define HIDDEN 5632
#define ROWS 4096  // BATCH*SEQ

__device__ __forceinline__ float b2f(u16 h) { return __uint_as_float(((u32)h) << 16); }
__device__ __forceinline__ u16 f2b(float f) {
  u32 u = __float_as_uint(f);
  return (u16)((u + 0x7fffu + ((u >> 16) & 1u)) >> 16);
}

// ---------------- fp32 -> bf16 elementwise ----------------
__global__ __launch_bounds__(256) void cvt_f2b(const float* __restrict__ in, u16* __restrict__ out, int n) {
  int i = (blockIdx.x * 256 + threadIdx.x) * 4;
  if (i < n) {
    float4 v = *(const float4*)(in + i);
    u32 p0 = (u32)f2b(v.x) | ((u32)f2b(v.y) << 16);
    u32 p1 = (u32)f2b(v.z) | ((u32)f2b(v.w) << 16);
    *(uint2*)(out + i) = make_uint2(p0, p1);
  }
}

// ---------------- fp32 [R,C] -> bf16 transposed [C,R] ----------------
__global__ __launch_bounds__(256) void cvtT(const float* __restrict__ in, u16* __restrict__ out,
                                            int Rr, int Cc) {
  __shared__ float t[32][33];
  int tx = threadIdx.x & 31, ty = threadIdx.x >> 5;
  int r0 = blockIdx.y * 32, c0 = blockIdx.x * 32;
#pragma unroll
  for (int rr = 0; rr < 4; ++rr)
    t[ty + rr * 8][tx] = in[(size_t)(r0 + ty + rr * 8) * Cc + c0 + tx];
  __syncthreads();
#pragma unroll
  for (int rr = 0; rr < 4; ++rr)
    out[(size_t)(c0 + ty + rr * 8) * Rr + r0 + tx] = f2b(t[tx][ty + rr * 8]);
}

// ================= 128^2 m97-structure GEMM (kept for oproj / down) =================
__device__ __forceinline__ void stage_tile(u16* lds, const u16* __restrict__ g,
                                           int row0, int col0, int ld, int wave, int lane) {
#pragma unroll
  for (int j = 0; j < 2; ++j) {
    int i = wave * 2 + j;
    const u16* gp = g + (size_t)(row0 + i * 16 + (lane >> 2)) * ld + col0 + (lane & 3) * 8;
    __builtin_amdgcn_global_load_lds((const __attribute__((address_space(1))) void*)gp,
                                     (__attribute__((address_space(3))) void*)(lds + i * 512),
                                     16, 0, 0);
  }
}

// EPI: 0 bf16 store; 1 fp32 C=acc+fp32 R; 2 bf16 C=silu(R)*acc; 3 fp32 C=acc+bf16 R; 4 QKV split
template <int EPI>
__global__ __launch_bounds__(256) void gemm_bt(const u16* __restrict__ A, const u16* __restrict__ Bt,
                                               const void* R_, void* C_, int M, int N, int K) {
  __shared__ u16 lA[2][4096];
  __shared__ u16 lB[2][4096];
  const int tid = threadIdx.x, lane = tid & 63, wave = tid >> 6;
  const int wm = wave >> 1, wn = wave & 1;
  const int gx = gridDim.x;
  const int nwg = gx * gridDim.y;
  const int id = blockIdx.y * gx + blockIdx.x;
  const int cpx = nwg >> 3;
  const int sw = (id & 7) * cpx + (id >> 3);
  const int m0 = (sw / gx) * 128, n0 = (sw % gx) * 128;
  const int rl = lane & 15, g = lane >> 4;

  stage_tile(lA[0], A, m0, 0, K, wave, lane);
  stage_tile(lB[0], Bt, n0, 0, K, wave, lane);

  f32x4 acc[4][4];
#pragma unroll
  for (int a = 0; a < 4; ++a)
#pragma unroll
    for (int b = 0; b < 4; ++b) acc[a][b] = (f32x4){0.f, 0.f, 0.f, 0.f};

  __syncthreads();

  const int nk = K / 32;
  for (int kt = 0; kt < nk; ++kt) {
    const int cur = kt & 1;
    if (kt + 1 < nk) {
      stage_tile(lA[cur ^ 1], A, m0, (kt + 1) * 32, K, wave, lane);
      stage_tile(lB[cur ^ 1], Bt, n0, (kt + 1) * 32, K, wave, lane);
    }
    bf16x8 af[4], bfr[4];
#pragma unroll
    for (int mi = 0; mi < 4; ++mi)
      af[mi] = *reinterpret_cast<const bf16x8*>(&lA[cur][(wm * 64 + mi * 16 + rl) * 32 + g * 8]);
#pragma unroll
    for (int ni = 0; ni < 4; ++ni)
      bfr[ni] = *reinterpret_cast<const bf16x8*>(&lB[cur][(wn * 64 + ni * 16 + rl) * 32 + g * 8]);
#pragma unroll
    for (int mi = 0; mi < 4; ++mi)
#pragma unroll
      for (int ni = 0; ni < 4; ++ni)
        acc[mi][ni] = __builtin_amdgcn_mfma_f32_16x16x32_bf16(af[mi], bfr[ni], acc[mi][ni], 0, 0, 0);
    __syncthreads();
  }

#pragma unroll
  for (int mi = 0; mi < 4; ++mi)
#pragma unroll
    for (int ni = 0; ni < 4; ++ni)
#pragma unroll
      for (int j = 0; j < 4; ++j) {
        size_t row = m0 + wm * 64 + mi * 16 + g * 4 + j;
        size_t col = n0 + wn * 64 + ni * 16 + rl;
        size_t idx = row * N + col;
        float v = acc[mi][ni][j];
        if (EPI == 0) {
          ((u16*)C_)[idx] = f2b(v);
        } else if (EPI == 1) {
          ((float*)C_)[idx] = v + ((const float*)R_)[idx];
        } else if (EPI == 2) {
          float av = b2f(((const u16*)R_)[idx]);
          ((u16*)C_)[idx] = f2b(v * av / (1.f + __expf(-av)));
        } else if (EPI == 3) {
          ((float*)C_)[idx] = v + b2f(((const u16*)R_)[idx]);
        } else {
          size_t di = (col >> 11) * (size_t)(ROWS * (size_t)DIM) + row * DIM + (col & (DIM - 1));
          ((u16*)C_)[di] = f2b(v);
        }
      }
}

// ================= 256^2 8-phase GEMM (m201 template, plain HIP) =================
// BM=BN=256, BK=64, 8 waves (2M x 4N), per-wave C = 128x64 (8mi x 4ni frags).
// LDS [buf][A/B][half(128 rows)][panel kk][row][slot] with st_16x32 XOR swizzle:
//   slot' = slot ^ (((row>>3)&1)<<1)  -- applied on global SOURCE at staging and on ds_read.
// 8 phases per iter (2 K-steps). Per phase: quadrant ds_reads, 1 half-tile stage,
// barrier, lgkmcnt(0)+sched_barrier, setprio(1), 16 MFMA, setprio(0), [vmcnt @ph3/ph7], barrier.
// Staging slots (iter i, k0=2i): ph0:A0(k0+1) ph1:A1(k0+1) ph2:B0(k0+2) ph3:B1(k0+2)
//   ph4:A0(k0+2) ph5:A1(k0+2) ph6:B0(k0+3) ph7:B1(k0+3); vmcnt(4) at ph3/ph7 (0 on last iter).
template <int EPI>
__global__ __launch_bounds__(512, 2) void gemm8p(const u16* __restrict__ A, const u16* __restrict__ Bt,
                                                 const void* R_, void* C_, int M, int N, int K) {
  __shared__ u16 L[2][2][2][8192];  // 128 KiB
  const int tid = threadIdx.x;
  const int lane = tid & 63, wid = tid >> 6;
  const int wr = wid >> 2, wc = wid & 3;
  const int rl = lane & 15, g = lane >> 4;
  const int s2 = ((rl >> 3) & 1) << 1;  // read-side swizzle term
  const int gx = gridDim.x;
  const int id = blockIdx.y * gx + blockIdx.x;
  const int cpx = (gx * gridDim.y) >> 3;
  const int sw = (id & 7) * cpx + (id >> 3);
  const int m0 = (sw / gx) * 256, n0 = (sw % gx) * 256;
  const int nk = K >> 6;

  const int srow = tid >> 2;                               // 0..127
  const int sslot = (tid & 3) ^ (((tid >> 5) & 1) << 1);   // pre-swizzled global slot

  auto SH = [&](int ks, int ab, int hf) {
    const u16* src = ab ? Bt : A;
    const u16* gp = src + (size_t)((ab ? n0 : m0) + hf * 128 + srow) * K + ks * 64 + sslot * 8;
#pragma unroll
    for (int kk = 0; kk < 2; ++kk)
      __builtin_amdgcn_global_load_lds(
          (const __attribute__((address_space(1))) void*)(gp + kk * 32),
          (__attribute__((address_space(3))) void*)&L[ks & 1][ab][hf][kk * 4096 + wid * 512],
          16, 0, 0);
  };

  f32x4 acc[8][4];
#pragma unroll
  for (int a = 0; a < 8; ++a)
#pragma unroll
    for (int b = 0; b < 4; ++b) acc[a][b] = (f32x4){0.f, 0.f, 0.f, 0.f};
  bf16x8 bf[4][2];

#define PHASE8(kst, q, STAGE, VMN)                                                              \
  do {                                                                                          \
    const int c_ = (kst) & 1;                                                                   \
    if ((q) == 0) {                                                                             \
      _Pragma("unroll") for (int ni = 0; ni < 4; ++ni)                                          \
          _Pragma("unroll") for (int kk = 0; kk < 2; ++kk)                                      \
              bf[ni][kk] = *(const bf16x8*)&L[c_][1][wc >> 1]                                   \
                  [kk * 4096 + ((wc & 1) * 64 + ni * 16 + rl) * 32 + (g ^ s2) * 8];             \
    }                                                                                           \
    bf16x8 af[2][2];                                                                            \
    _Pragma("unroll") for (int mm = 0; mm < 2; ++mm)                                            \
        _Pragma("unroll") for (int kk = 0; kk < 2; ++kk)                                        \
            af[mm][kk] = *(const bf16x8*)&L[c_][0][wr]                                          \
                [kk * 4096 + (((q) * 2 + mm) * 16 + rl) * 32 + (g ^ s2) * 8];                   \
    STAGE;                                                                                      \
    __builtin_amdgcn_s_barrier();                                                               \
    asm volatile("s_waitcnt lgkmcnt(0)" ::: "memory");                                          \
    __builtin_amdgcn_sched_barrier(0);                                                          \
    __builtin_amdgcn_s_setprio(1);                                                              \
    _Pragma("unroll") for (int kk = 0; kk < 2; ++kk)                                            \
        _Pragma("unroll") for (int mm = 0; mm < 2; ++mm)                                        \
            _Pragma("unroll") for (int ni = 0; ni < 4; ++ni)                                    \
                acc[(q) * 2 + mm][ni] = __builtin_amdgcn_mfma_f32_16x16x32_bf16(                \
                    af[mm][kk], bf[ni][kk], acc[(q) * 2 + mm][ni], 0, 0, 0);                    \
    __builtin_amdgcn_s_setprio(0);                                                              \
    if ((VMN) == 4) asm volatile("s_waitcnt vmcnt(4)" ::: "memory");                            \
    else if ((VMN) == 0) asm volatile("s_waitcnt vmcnt(0)" ::: "memory");                       \
    __builtin_amdgcn_s_barrier();                                                               \
  } while (0)

  // prologue: A(0), B(0), B(1) = 12 gloads/wave-pair; keep newest 4 in flight
  SH(0, 0, 0); SH(0, 0, 1); SH(0, 1, 0); SH(0, 1, 1); SH(1, 1, 0); SH(1, 1, 1);
  asm volatile("s_waitcnt vmcnt(4)" ::: "memory");
  __builtin_amdgcn_s_barrier();

  const int nk2 = nk >> 1;
  for (int i = 0; i < nk2; ++i) {
    const int k0 = 2 * i, k1 = 2 * i + 1;
    const bool st2 = (k0 + 2) < nk, st3 = (k0 + 3) < nk;
    PHASE8(k0, 0, SH(k1, 0, 0), -1);
    PHASE8(k0, 1, SH(k1, 0, 1), -1);
    PHASE8(k0, 2, if (st2) SH(k0 + 2, 1, 0), -1);
    PHASE8(k0, 3, if (st2) SH(k0 + 2, 1, 1), st2 ? 4 : 0);
    PHASE8(k1, 0, if (st2) SH(k0 + 2, 0, 0), -1);
    PHASE8(k1, 1, if (st2) SH(k0 + 2, 0, 1), -1);
    PHASE8(k1, 2, if (st3) SH(k0 + 3, 1, 0), -1);
    PHASE8(k1, 3, if (st3) SH(k0 + 3, 1, 1), st2 ? 4 : 0);
  }
#undef PHASE8

#pragma unroll
  for (int mi = 0; mi < 8; ++mi)
#pragma unroll
    for (int ni = 0; ni < 4; ++ni)
#pragma unroll
      for (int j = 0; j < 4; ++j) {
        size_t row = m0 + wr * 128 + mi * 16 + g * 4 + j;
        size_t col = n0 + wc * 64 + ni * 16 + rl;
        size_t idx = row * N + col;
        float v = acc[mi][ni][j];
        if (EPI == 0) {
          ((u16*)C_)[idx] = f2b(v);
        } else if (EPI == 2) {
          float av = b2f(((const u16*)R_)[idx]);
          ((u16*)C_)[idx] = f2b(v * av / (1.f + __expf(-av)));
        } else {  // EPI == 4: QKV split store
          size_t di = (col >> 11) * (size_t)(ROWS * (size_t)DIM) + row * DIM + (col & (DIM - 1));
          ((u16*)C_)[di] = f2b(v);
        }
      }
}

// ---------------- V [B,S,H,D] bf16 -> Vt [B,H,D,S] bf16 ----------------
__global__ __launch_bounds__(256) void vtrans(const u16* __restrict__ V, u16* __restrict__ Vt) {
  __shared__ u16 t[32][33];
  int tx = threadIdx.x & 31, ty = threadIdx.x >> 5;
  int s0 = blockIdx.x * 32, d0 = blockIdx.y * 32;
  int bh = blockIdx.z, b = bh >> 4, h = bh & 15;
#pragma unroll
  for (int rr = 0; rr < 4; ++rr)
    t[ty + rr * 8][tx] = V[(size_t)(b * SEQ + s0 + ty + rr * 8) * DIM + h * HDIM + d0 + tx];
  __syncthreads();
#pragma unroll
  for (int rr = 0; rr < 4; ++rr)
    Vt[(size_t)(bh * HDIM + d0 + ty + rr * 8) * SEQ + s0 + tx] = t[tx][ty + rr * 8];
}

// ---------------- RoPE in-place on bf16 q,k; fp32 cos/sin; q scaled 1/sqrt(HDIM) ----------------
__global__ __launch_bounds__(256) void rope_kernel(u16* __restrict__ Q, u16* __restrict__ Kv,
                                                   const float* __restrict__ Cz, const float* __restrict__ Sz) {
  int t = blockIdx.x * 256 + threadIdx.x;
  int i = t & 63;
  int hh = (t >> 6) & 15;
  int row = t >> 10;
  int s = row & (SEQ - 1);
  float c = Cz[s * 64 + i], sn = Sz[s * 64 + i];
  size_t off = (size_t)row * DIM + hh * HDIM + 2 * i;
  const float sc = 0.08838834764831843f;

  u32 qp = *(const u32*)(Q + off);
  float q0 = b2f((u16)qp), q1 = b2f((u16)(qp >> 16));
  float o0 = (q0 * c - q1 * sn) * sc, o1 = (q0 * sn + q1 * c) * sc;
  *(u32*)(Q + off) = (u32)f2b(o0) | ((u32)f2b(o1) << 16);

  u32 kp = *(const u32*)(Kv + off);
  float k0 = b2f((u16)kp), k1 = b2f((u16)(kp >> 16));
  o0 = k0 * c - k1 * sn; o1 = k0 * sn + k1 * c;
  *(u32*)(Kv + off) = (u32)f2b(o0) | ((u32)f2b(o1) << 16);
}

// ---------------- flash attention (causal), unchanged from round 5 ----------------
__device__ __forceinline__ void attn_stage(u16* lk, u16* lv, const u16* __restrict__ Kg,
                                           const u16* __restrict__ Vg, int b, int h, int bh,
                                           int t, int w, int lane) {
  const int r4 = lane >> 2;
  const int gsw = (lane & 3) ^ (r4 & 3);
#pragma unroll
  for (int j = 0; j < 4; ++j) {
    const u16* gp = Kg + (size_t)(b * SEQ + t * 64 + j * 16 + r4) * DIM +
                    h * HDIM + w * 32 + gsw * 8;
    __builtin_amdgcn_global_load_lds((const __attribute__((address_space(1))) void*)gp,
                                     (__attribute__((address_space(3))) void*)(lk + w * 2048 + j * 512),
                                     16, 0, 0);
  }
#pragma unroll
  for (int j = 0; j < 4; ++j) {
    int id = w * 4 + j, kc2 = id >> 3, rg = id & 7;
    const u16* gp = Vg + (size_t)(bh * HDIM + rg * 16 + r4) * SEQ +
                    t * 64 + kc2 * 32 + gsw * 8;
    __builtin_amdgcn_global_load_lds((const __attribute__((address_space(1))) void*)gp,
                                     (__attribute__((address_space(3))) void*)(lv + kc2 * 4096 + rg * 512),
                                     16, 0, 0);
  }
}

__device__ __forceinline__ void attn_tile(const bf16x8* qf, float* m, float* l, f32x4* oacc,
                                          int qg0, int t, bool diag,
                                          const u16* lk, const u16* lv, u16 (*pl)[72],
                                          int rl, int g) {
  const int gx8 = (g ^ (rl & 3)) * 8;
  f32x4 s[4];
#pragma unroll
  for (int ct = 0; ct < 4; ++ct) s[ct] = (f32x4){0.f, 0.f, 0.f, 0.f};
#pragma unroll
  for (int ct = 0; ct < 4; ++ct)
#pragma unroll
    for (int kc = 0; kc < 4; ++kc) {
      bf16x8 kf = *reinterpret_cast<const bf16x8*>(&lk[kc * 2048 + (ct * 16 + rl) * 32 + gx8]);
      s[ct] = __builtin_amdgcn_mfma_f32_16x16x32_bf16(qf[kc], kf, s[ct], 0, 0, 0);
    }
  if (diag) {
#pragma unroll
    for (int ct = 0; ct < 4; ++ct) {
      int kg = t * 64 + ct * 16 + rl;
#pragma unroll
      for (int j = 0; j < 4; ++j)
        if (kg > qg0 + j) s[ct][j] = -1e30f;
    }
  }
  float mx[4], al[4];
#pragma unroll
  for (int j = 0; j < 4; ++j)
    mx[j] = fmaxf(fmaxf(s[0][j], s[1][j]), fmaxf(s[2][j], s[3][j]));
#pragma unroll
  for (int off = 1; off < 16; off <<= 1)
#pragma unroll
    for (int j = 0; j < 4; ++j) mx[j] = fmaxf(mx[j], __shfl_xor(mx[j], off));
#pragma unroll
  for (int j = 0; j < 4; ++j) {
    float mn = fmaxf(m[j], mx[j]);
    al[j] = __expf(m[j] - mn);
    m[j] = mn;
  }
  float rs[4] = {0.f, 0.f, 0.f, 0.f};
#pragma unroll
  for (int ct = 0; ct < 4; ++ct)
#pragma unroll
    for (int j = 0; j < 4; ++j) {
      float p = __expf(s[ct][j] - m[j]);
      s[ct][j] = p;
      rs[j] += p;
    }
#pragma unroll
  for (int off = 1; off < 16; off <<= 1)
#pragma unroll
    for (int j = 0; j < 4; ++j) rs[j] += __shfl_xor(rs[j], off);
#pragma unroll
  for (int j = 0; j < 4; ++j) l[j] = l[j] * al[j] + rs[j];
#pragma unroll
  for (int dt = 0; dt < 8; ++dt)
#pragma unroll
    for (int j = 0; j < 4; ++j) oacc[dt][j] *= al[j];

#pragma unroll
  for (int ct = 0; ct < 4; ++ct)
#pragma unroll
    for (int j = 0; j < 4; ++j) pl[g * 4 + j][ct * 16 + rl] = f2b(s[ct][j]);

  bf16x8 pa[2];
#pragma unroll
  for (int kc2 = 0; kc2 < 2; ++kc2)
    pa[kc2] = *reinterpret_cast<const bf16x8*>(&pl[rl][kc2 * 32 + g * 8]);

#pragma unroll
  for (int dt = 0; dt < 8; ++dt)
#pragma unroll
    for (int kc2 = 0; kc2 < 2; ++kc2) {
      bf16x8 vf = *reinterpret_cast<const bf16x8*>(&lv[kc2 * 4096 + (dt * 16 + rl) * 32 + gx8]);
      oacc[dt] = __builtin_amdgcn_mfma_f32_16x16x32_bf16(pa[kc2], vf, oacc[dt], 0, 0, 0);
    }
}

__global__ __launch_bounds__(256) void attn_kernel(const u16* __restrict__ Q, const u16* __restrict__ Kp,
                                                   const u16* __restrict__ Vt, u16* __restrict__ O) {
  const int lane = threadIdx.x & 63;
  const int w = threadIdx.x >> 6;
  const int id = blockIdx.y * 16 + blockIdx.x;
  const int sw = (id & 7) * 64 + (id >> 3);
  const int qa = sw & 15;
  const int qb = 31 - qa;
  const int bh = sw >> 4;
  const int b = bh >> 4, h = bh & 15;
  const int rl = lane & 15, g = lane >> 4;

  __shared__ u16 lK[2][8192];
  __shared__ u16 lV[2][8192];
  __shared__ u16 plds[4][16][72];

  const size_t qrowA = (size_t)b * SEQ + qa * 64 + w * 16;
  const size_t qrowB = (size_t)b * SEQ + qb * 64 + w * 16;
  bf16x8 qfA[4], qfB[4];
#pragma unroll
  for (int kc = 0; kc < 4; ++kc) {
    qfA[kc] = *reinterpret_cast<const bf16x8*>(Q + (qrowA + rl) * DIM + h * HDIM + kc * 32 + g * 8);
    qfB[kc] = *reinterpret_cast<const bf16x8*>(Q + (qrowB + rl) * DIM + h * HDIM + kc * 32 + g * 8);
  }

  float mA[4], lA_[4], mB[4], lB_[4];
  f32x4 oA[8], oB[8];
#pragma unroll
  for (int j = 0; j < 4; ++j) { mA[j] = -1e30f; lA_[j] = 0.f; mB[j] = -1e30f; lB_[j] = 0.f; }
#pragma unroll
  for (int dt = 0; dt < 8; ++dt) { oA[dt] = (f32x4){0.f, 0.f, 0.f, 0.f}; oB[dt] = (f32x4){0.f, 0.f, 0.f, 0.f}; }

  const int qg0A = qa * 64 + w * 16 + g * 4;
  const int qg0B = qb * 64 + w * 16 + g * 4;

  attn_stage(lK[0], lV[0], Kp, Vt, b, h, bh, 0, w, lane);

  int buf = 0;
  for (int t = 0; t <= qb; ++t) {
    if (t < qb) {
      attn_stage(lK[buf ^ 1], lV[buf ^ 1], Kp, Vt, b, h, bh, t + 1, w, lane);
      asm volatile("s_waitcnt vmcnt(8)" ::: "memory");
    } else {
      asm volatile("s_waitcnt vmcnt(0)" ::: "memory");
    }
    __builtin_amdgcn_s_barrier();
    __builtin_amdgcn_sched_barrier(0);
    attn_tile(qfB, mB, lB_, oB, qg0B, t, t == qb, lK[buf], lV[buf], plds[w], rl, g);
    if (t <= qa)
      attn_tile(qfA, mA, lA_, oA, qg0A, t, t == qa, lK[buf], lV[buf], plds[w], rl, g);
    asm volatile("s_waitcnt lgkmcnt(0)" ::: "memory");
    __builtin_amdgcn_sched_barrier(0);
    __builtin_amdgcn_s_barrier();
    buf ^= 1;
  }

  float invA[4], invB[4];
#pragma unroll
  for (int j = 0; j < 4; ++j) { invA[j] = 1.f / lA_[j]; invB[j] = 1.f / lB_[j]; }
#pragma unroll
  for (int dt = 0; dt < 8; ++dt)
#pragma unroll
    for (int j = 0; j < 4; ++j) {
      O[(qrowA + g * 4 + j) * DIM + h * HDIM + dt * 16 + rl] = f2b(oA[dt][j] * invA[j]);
      O[(qrowB + g * 4 + j) * DIM + h * HDIM + dt * 16 + rl] = f2b(oB[dt][j] * invB[j]);
    }
}

// ---------------- RMSNorm: fp32 in, fp32 weight; out bf16 or fp32 ----------------
__global__ __launch_bounds__(256) void rmsnorm_to_bf16(const float* __restrict__ X, const float* __restrict__ W,
                                                       u16* __restrict__ O) {
  int row = blockIdx.x, tid = threadIdx.x;
  const float* xr = X + (size_t)row * DIM + tid * 8;
  float4 a = *(const float4*)xr;
  float4 bq = *(const float4*)(xr + 4);
  float v[8] = {a.x, a.y, a.z, a.w, bq.x, bq.y, bq.z, bq.w};
  float ss = 0.f;
#pragma unroll
  for (int j = 0; j < 8; ++j) ss += v[j] * v[j];
#pragma unroll
  for (int off = 32; off; off >>= 1) ss += __shfl_xor(ss, off);
  __shared__ float wss[4];
  int wave = tid >> 6, lane = tid & 63;
  if (lane == 0) wss[wave] = ss;
  __syncthreads();
  float r = rsqrtf((wss[0] + wss[1] + wss[2] + wss[3]) * (1.f / DIM) + 1e-6f);
  float4 wa = *(const float4*)(W + tid * 8);
  float4 wb = *(const float4*)(W + tid * 8 + 4);
  float wv[8] = {wa.x, wa.y, wa.z, wa.w, wb.x, wb.y, wb.z, wb.w};
  uint4 ou;
  ou.x = (u32)f2b(v[0] * r * wv[0]) | ((u32)f2b(v[1] * r * wv[1]) << 16);
  ou.y = (u32)f2b(v[2] * r * wv[2]) | ((u32)f2b(v[3] * r * wv[3]) << 16);
  ou.z = (u32)f2b(v[4] * r * wv[4]) | ((u32)f2b(v[5] * r * wv[5]) << 16);
  ou.w = (u32)f2b(v[6] * r * wv[6]) | ((u32)f2b(v[7] * r * wv[7]) << 16);
  *(uint4*)(O + (size_t)row * DIM + tid * 8) = ou;
}

__global__ __launch_bounds__(256) void rmsnorm_to_f32(const float* __restrict__ X, const float* __restrict__ W,
                                                      float* __restrict__ O) {
  int row = blockIdx.x, tid = threadIdx.x;
  const float* xr = X + (size_t)row * DIM + tid * 8;
  float4 a = *(const float4*)xr;
  float4 bq = *(const float4*)(xr + 4);
  float v[8] = {a.x, a.y, a.z, a.w, bq.x, bq.y, bq.z, bq.w};
  float ss = 0.f;
#pragma unroll
  for (int j = 0; j < 8; ++j) ss += v[j] * v[j];
#pragma unroll
  for (int off = 32; off; off >>= 1) ss += __shfl_xor(ss, off);
  __shared__ float wss[4];
  int wave = tid >> 6, lane = tid & 63;
  if (lane == 0) wss[wave] = ss;
  __syncthreads();
  float r = rsqrtf((wss[0] + wss[1] + wss[2] + wss[3]) * (1.f / DIM) + 1e-6f);
  float4 wa = *(const float4*)(W + tid * 8);
  float4 wb = *(const float4*)(W + tid * 8 + 4);
  float wv[8] = {wa.x, wa.y, wa.z, wa.w, wb.x, wb.y, wb.z, wb.w};
  float4 o0 = {v[0] * r * wv[0], v[1] * r * wv[1], v[2] * r * wv[2], v[3] * r * wv[3]};
  float4 o1 = {v[4] * r * wv[4], v[5] * r * wv[5], v[6] * r * wv[6], v[7] * r * wv[7]};
  *(float4*)(O + (size_t)row * DIM + tid * 8) = o0;
  *(float4*)(O + (size_t)row * DIM + tid * 8 + 4) = o1;
}

// ---------------- launch ----------------
// Workspace layout (u16 units), peak 73.4M u16 = 146.8 MB (proven safe):
//   [0,SZ) xb -> later x1f/x2f (fp32 over [0,2SZ)); [SZ,2SZ) q; [2SZ,3SZ) k;
//   [3SZ,4SZ) v; [4SZ,5SZ) vt; [5SZ,6SZ) hb; [6SZ,+23.07M) weights (time-muxed)
extern "C" void kernel_launch(void* const* d_in, const int* in_sizes, int n_in,
                              void* d_out, int out_size, void* d_ws, size_t ws_size,
                              hipStream_t stream) {
  const float* x     = (const float*)d_in[0];
  const float* wq    = (const float*)d_in[1];
  const float* wk    = (const float*)d_in[2];
  const float* wv    = (const float*)d_in[3];
  const float* wo    = (const float*)d_in[4];
  const float* w_mlp = (const float*)d_in[5];
  const float* v_mlp = (const float*)d_in[6];
  const float* w2    = (const float*)d_in[7];
  const float* n1w   = (const float*)d_in[8];
  const float* n2w   = (const float*)d_in[9];
  const float* fcos  = (const float*)d_in[10];
  const float* fsin  = (const float*)d_in[11];

  u16* ws = (u16*)d_ws;
  const size_t SZ = (size_t)ROWS * DIM;
  const size_t DD = (size_t)DIM * DIM;
  const size_t DH = (size_t)DIM * HIDDEN;

  u16* xb  = ws;
  u16* q   = ws + SZ;
  u16* k   = ws + 2 * SZ;
  u16* v   = ws + 3 * SZ;
  u16* vt  = ws + 4 * SZ;
  u16* hb  = ws + 5 * SZ;
  u16* W   = ws + 6 * SZ;
  u16* wqT = W;
  u16* wkT = W + DD;
  u16* wvT = W + 2 * DD;
  u16* woT = W + 3 * DD;
  u16* wmb = W;
  u16* vmb = W + DH;
  u16* w2b = W;
  float* x1f = (float*)ws;
  float* x2f = (float*)ws;
  u16* ba  = ws + 2 * SZ;

  dim3 blk(256);
  dim3 blk8(512);

  // phase 0: input + attn weight conversion
  cvt_f2b<<<(int)(SZ / 4 / 256), blk, 0, stream>>>(x, xb, (int)SZ);
  dim3 gT(DIM / 32, DIM / 32);
  cvtT<<<gT, blk, 0, stream>>>(wq, wqT, DIM, DIM);
  cvtT<<<gT, blk, 0, stream>>>(wk, wkT, DIM, DIM);
  cvtT<<<gT, blk, 0, stream>>>(wv, wvT, DIM, DIM);
  cvtT<<<gT, blk, 0, stream>>>(wo, woT, DIM, DIM);

  // fused QKV projection: 256^2 8-phase, split store into q,k,v
  dim3 gQKV(3 * DIM / 256, ROWS / 256);  // (24, 16) = 384 blocks
  gemm8p<4><<<gQKV, blk8, 0, stream>>>(xb, W, nullptr, q, ROWS, 3 * DIM, DIM);

  cvt_f2b<<<(int)(DH / 4 / 256), blk, 0, stream>>>(w_mlp, wmb, (int)DH);

  rope_kernel<<<(ROWS * NHEAD * 64) / 256, blk, 0, stream>>>(q, k, fcos, fsin);
  vtrans<<<dim3(SEQ / 32, HDIM / 32, BATCH * NHEAD), blk, 0, stream>>>(v, vt);

  attn_kernel<<<dim3(16, BATCH * NHEAD), blk, 0, stream>>>(q, k, vt, v);

  // o-proj + fp32 residual x -> x1f (128^2 kernel: 128-tile grid too small for 256^2)
  dim3 gP(DIM / 128, ROWS / 128);
  gemm_bt<1><<<gP, blk, 0, stream>>>(v, woT, x, x1f, ROWS, DIM, DIM);

  cvt_f2b<<<(int)(DH / 4 / 256), blk, 0, stream>>>(v_mlp, vmb, (int)DH);

  rmsnorm_to_bf16<<<ROWS, blk, 0, stream>>>(x1f, n1w, hb);

  // MLP up + gate: 256^2 8-phase
  dim3 gM8(HIDDEN / 256, ROWS / 256);  // (22, 16) = 352 blocks
  gemm8p<0><<<gM8, blk8, 0, stream>>>(hb, wmb, nullptr, ba, ROWS, HIDDEN, DIM);
  gemm8p<2><<<gM8, blk8, 0, stream>>>(hb, vmb, ba, ba, ROWS, HIDDEN, DIM);

  cvt_f2b<<<(int)(DH / 4 / 256), blk, 0, stream>>>(w2, w2b, (int)DH);

  // down-proj + bf16 residual h -> x2f (128^2 kernel)
  gemm_bt<3><<<gP, blk, 0, stream>>>(ba, w2b, hb, x2f, ROWS, DIM, HIDDEN);
  rmsnorm_to_f32<<<ROWS, blk, 0, stream>>>(x2f, n2w, (float*)d_out);
}

// Round 7
// 813.775 us; speedup vs baseline: 1.0666x; 1.0666x over previous
//
#include <hip/hip_runtime.h>

typedef unsigned short u16;
typedef unsigned int u32;
typedef float f32x4 __attribute__((ext_vector_type(4)));
typedef short bf16x8 __attribute__((ext_vector_type(8)));

#define DIM 2048
#define SEQ 2048
#define NHEAD 16
#define HDIM 128
#define BATCH 2
#define HIDDEN 5632
#define ROWS 4096  // BATCH*SEQ

__device__ __forceinline__ float b2f(u16 h) { return __uint_as_float(((u32)h) << 16); }
__device__ __forceinline__ u16 f2b(float f) {
  u32 u = __float_as_uint(f);
  return (u16)((u + 0x7fffu + ((u >> 16) & 1u)) >> 16);
}

// ---------------- fp32 -> bf16 elementwise ----------------
__global__ __launch_bounds__(256) void cvt_f2b(const float* __restrict__ in, u16* __restrict__ out, int n) {
  int i = (blockIdx.x * 256 + threadIdx.x) * 4;
  if (i < n) {
    float4 v = *(const float4*)(in + i);
    u32 p0 = (u32)f2b(v.x) | ((u32)f2b(v.y) << 16);
    u32 p1 = (u32)f2b(v.z) | ((u32)f2b(v.w) << 16);
    *(uint2*)(out + i) = make_uint2(p0, p1);
  }
}

// ---------------- fp32 [R,C] -> bf16 transposed [C,R] ----------------
__global__ __launch_bounds__(256) void cvtT(const float* __restrict__ in, u16* __restrict__ out,
                                            int Rr, int Cc) {
  __shared__ float t[32][33];
  int tx = threadIdx.x & 31, ty = threadIdx.x >> 5;
  int r0 = blockIdx.y * 32, c0 = blockIdx.x * 32;
#pragma unroll
  for (int rr = 0; rr < 4; ++rr)
    t[ty + rr * 8][tx] = in[(size_t)(r0 + ty + rr * 8) * Cc + c0 + tx];
  __syncthreads();
#pragma unroll
  for (int rr = 0; rr < 4; ++rr)
    out[(size_t)(c0 + ty + rr * 8) * Rr + r0 + tx] = f2b(t[tx][ty + rr * 8]);
}

// ================= 128^2 m97-structure GEMM (all GEMMs; gemm8p reverted) =================
__device__ __forceinline__ void stage_tile(u16* lds, const u16* __restrict__ g,
                                           int row0, int col0, int ld, int wave, int lane) {
#pragma unroll
  for (int j = 0; j < 2; ++j) {
    int i = wave * 2 + j;
    const u16* gp = g + (size_t)(row0 + i * 16 + (lane >> 2)) * ld + col0 + (lane & 3) * 8;
    __builtin_amdgcn_global_load_lds((const __attribute__((address_space(1))) void*)gp,
                                     (__attribute__((address_space(3))) void*)(lds + i * 512),
                                     16, 0, 0);
  }
}

// EPI: 0 bf16 store; 1 fp32 C=acc+fp32 R; 2 bf16 C=silu(R)*acc; 3 fp32 C=acc+bf16 R; 4 QKV split
template <int EPI>
__global__ __launch_bounds__(256) void gemm_bt(const u16* __restrict__ A, const u16* __restrict__ Bt,
                                               const void* R_, void* C_, int M, int N, int K) {
  __shared__ u16 lA[2][4096];
  __shared__ u16 lB[2][4096];
  const int tid = threadIdx.x, lane = tid & 63, wave = tid >> 6;
  const int wm = wave >> 1, wn = wave & 1;
  const int gx = gridDim.x;
  const int nwg = gx * gridDim.y;
  const int id = blockIdx.y * gx + blockIdx.x;
  const int cpx = nwg >> 3;
  const int sw = (id & 7) * cpx + (id >> 3);
  const int m0 = (sw / gx) * 128, n0 = (sw % gx) * 128;
  const int rl = lane & 15, g = lane >> 4;

  stage_tile(lA[0], A, m0, 0, K, wave, lane);
  stage_tile(lB[0], Bt, n0, 0, K, wave, lane);

  f32x4 acc[4][4];
#pragma unroll
  for (int a = 0; a < 4; ++a)
#pragma unroll
    for (int b = 0; b < 4; ++b) acc[a][b] = (f32x4){0.f, 0.f, 0.f, 0.f};

  __syncthreads();

  const int nk = K / 32;
  for (int kt = 0; kt < nk; ++kt) {
    const int cur = kt & 1;
    if (kt + 1 < nk) {
      stage_tile(lA[cur ^ 1], A, m0, (kt + 1) * 32, K, wave, lane);
      stage_tile(lB[cur ^ 1], Bt, n0, (kt + 1) * 32, K, wave, lane);
    }
    bf16x8 af[4], bfr[4];
#pragma unroll
    for (int mi = 0; mi < 4; ++mi)
      af[mi] = *reinterpret_cast<const bf16x8*>(&lA[cur][(wm * 64 + mi * 16 + rl) * 32 + g * 8]);
#pragma unroll
    for (int ni = 0; ni < 4; ++ni)
      bfr[ni] = *reinterpret_cast<const bf16x8*>(&lB[cur][(wn * 64 + ni * 16 + rl) * 32 + g * 8]);
#pragma unroll
    for (int mi = 0; mi < 4; ++mi)
#pragma unroll
      for (int ni = 0; ni < 4; ++ni)
        acc[mi][ni] = __builtin_amdgcn_mfma_f32_16x16x32_bf16(af[mi], bfr[ni], acc[mi][ni], 0, 0, 0);
    __syncthreads();
  }

#pragma unroll
  for (int mi = 0; mi < 4; ++mi)
#pragma unroll
    for (int ni = 0; ni < 4; ++ni)
#pragma unroll
      for (int j = 0; j < 4; ++j) {
        size_t row = m0 + wm * 64 + mi * 16 + g * 4 + j;
        size_t col = n0 + wn * 64 + ni * 16 + rl;
        size_t idx = row * N + col;
        float v = acc[mi][ni][j];
        if (EPI == 0) {
          ((u16*)C_)[idx] = f2b(v);
        } else if (EPI == 1) {
          ((float*)C_)[idx] = v + ((const float*)R_)[idx];
        } else if (EPI == 2) {
          float av = b2f(((const u16*)R_)[idx]);
          ((u16*)C_)[idx] = f2b(v * av / (1.f + __expf(-av)));
        } else if (EPI == 3) {
          ((float*)C_)[idx] = v + b2f(((const u16*)R_)[idx]);
        } else {
          size_t di = (col >> 11) * (size_t)(ROWS * (size_t)DIM) + row * DIM + (col & (DIM - 1));
          ((u16*)C_)[di] = f2b(v);
        }
      }
}

// ---------------- V [B,S,H,D] bf16 -> Vt [B,H,D,S] bf16 ----------------
__global__ __launch_bounds__(256) void vtrans(const u16* __restrict__ V, u16* __restrict__ Vt) {
  __shared__ u16 t[32][33];
  int tx = threadIdx.x & 31, ty = threadIdx.x >> 5;
  int s0 = blockIdx.x * 32, d0 = blockIdx.y * 32;
  int bh = blockIdx.z, b = bh >> 4, h = bh & 15;
#pragma unroll
  for (int rr = 0; rr < 4; ++rr)
    t[ty + rr * 8][tx] = V[(size_t)(b * SEQ + s0 + ty + rr * 8) * DIM + h * HDIM + d0 + tx];
  __syncthreads();
#pragma unroll
  for (int rr = 0; rr < 4; ++rr)
    Vt[(size_t)(bh * HDIM + d0 + ty + rr * 8) * SEQ + s0 + tx] = t[tx][ty + rr * 8];
}

// ---------------- RoPE in-place on bf16 q,k; fp32 cos/sin; q scaled 1/sqrt(HDIM) ----------------
__global__ __launch_bounds__(256) void rope_kernel(u16* __restrict__ Q, u16* __restrict__ Kv,
                                                   const float* __restrict__ Cz, const float* __restrict__ Sz) {
  int t = blockIdx.x * 256 + threadIdx.x;
  int i = t & 63;
  int hh = (t >> 6) & 15;
  int row = t >> 10;
  int s = row & (SEQ - 1);
  float c = Cz[s * 64 + i], sn = Sz[s * 64 + i];
  size_t off = (size_t)row * DIM + hh * HDIM + 2 * i;
  const float sc = 0.08838834764831843f;

  u32 qp = *(const u32*)(Q + off);
  float q0 = b2f((u16)qp), q1 = b2f((u16)(qp >> 16));
  float o0 = (q0 * c - q1 * sn) * sc, o1 = (q0 * sn + q1 * c) * sc;
  *(u32*)(Q + off) = (u32)f2b(o0) | ((u32)f2b(o1) << 16);

  u32 kp = *(const u32*)(Kv + off);
  float k0 = b2f((u16)kp), k1 = b2f((u16)(kp >> 16));
  o0 = k0 * c - k1 * sn; o1 = k0 * sn + k1 * c;
  *(u32*)(Kv + off) = (u32)f2b(o0) | ((u32)f2b(o1) << 16);
}

// ---------------- flash attention (causal): 1 q-tile/block, single-buffered K/V ----------------
// 1024 blocks (32 qt x 32 bh), 4 waves, LDS 41KB -> 3 blocks/CU (12 waves/CU).
// Dynamic backfill over XCD-swizzled blocks balances the causal workload; K/V L2-hot
// (4 bh per XCD). Per-iter split schedule with counted per-wave vmcnt, each followed
// by a barrier (staged LDS parts come from other waves' loads):
//   vmcnt(4)+bar [K(t) in] -> QK^T -> lgkm+bar -> stageK(t+1) -> vmcnt(4|0)+bar [V(t) in]
//   -> softmax+PV -> lgkm+bar -> stageV(t+1)
__device__ __forceinline__ void stage_K(u16* lk, const u16* __restrict__ Kg,
                                        int b, int h, int t, int w, int lane) {
  const int r4 = lane >> 2;
  const int gsw = (lane & 3) ^ (r4 & 3);
#pragma unroll
  for (int j = 0; j < 4; ++j) {
    const u16* gp = Kg + (size_t)(b * SEQ + t * 64 + j * 16 + r4) * DIM +
                    h * HDIM + w * 32 + gsw * 8;
    __builtin_amdgcn_global_load_lds((const __attribute__((address_space(1))) void*)gp,
                                     (__attribute__((address_space(3))) void*)(lk + w * 2048 + j * 512),
                                     16, 0, 0);
  }
}

__device__ __forceinline__ void stage_V(u16* lv, const u16* __restrict__ Vg,
                                        int bh, int t, int w, int lane) {
  const int r4 = lane >> 2;
  const int gsw = (lane & 3) ^ (r4 & 3);
#pragma unroll
  for (int j = 0; j < 4; ++j) {
    int id = w * 4 + j, kc2 = id >> 3, rg = id & 7;
    const u16* gp = Vg + (size_t)(bh * HDIM + rg * 16 + r4) * SEQ +
                    t * 64 + kc2 * 32 + gsw * 8;
    __builtin_amdgcn_global_load_lds((const __attribute__((address_space(1))) void*)gp,
                                     (__attribute__((address_space(3))) void*)(lv + kc2 * 4096 + rg * 512),
                                     16, 0, 0);
  }
}

__global__ __launch_bounds__(256, 3) void attn_kernel(const u16* __restrict__ Q, const u16* __restrict__ Kp,
                                                      const u16* __restrict__ Vt, u16* __restrict__ O) {
  const int lane = threadIdx.x & 63;
  const int w = threadIdx.x >> 6;
  // XCD-bijective swizzle: 1024 blocks, 128/XCD -> 4 bh per XCD (K/V L2-resident)
  const int id = blockIdx.y * 32 + blockIdx.x;
  const int sw = (id & 7) * 128 + (id >> 3);
  const int qt = sw & 31;
  const int bh = sw >> 5;
  const int b = bh >> 4, h = bh & 15;
  const int rl = lane & 15, g = lane >> 4;
  const int gx8 = (g ^ (rl & 3)) * 8;  // de-swizzled LDS slot

  __shared__ u16 lK[8192];
  __shared__ u16 lV[8192];
  __shared__ u16 plds[4][16][72];

  const size_t qrow = (size_t)b * SEQ + qt * 64 + w * 16;
  bf16x8 qf[4];
#pragma unroll
  for (int kc = 0; kc < 4; ++kc)
    qf[kc] = *reinterpret_cast<const bf16x8*>(Q + (qrow + rl) * DIM + h * HDIM + kc * 32 + g * 8);

  float m[4], l[4];
  f32x4 oacc[8];
#pragma unroll
  for (int j = 0; j < 4; ++j) { m[j] = -1e30f; l[j] = 0.f; }
#pragma unroll
  for (int dt = 0; dt < 8; ++dt) oacc[dt] = (f32x4){0.f, 0.f, 0.f, 0.f};

  const int qg0 = qt * 64 + w * 16 + g * 4;
  const int tmax = qt;

  stage_K(lK, Kp, b, h, 0, w, lane);
  stage_V(lV, Vt, bh, 0, w, lane);

  for (int t = 0; t <= tmax; ++t) {
    // --- K(t) ready (V(t) = newest 4 loads still in flight) ---
    asm volatile("s_waitcnt vmcnt(4)" ::: "memory");
    __builtin_amdgcn_s_barrier();
    __builtin_amdgcn_sched_barrier(0);

    // --- S = Q K^T ---
    f32x4 s[4];
#pragma unroll
    for (int ct = 0; ct < 4; ++ct) s[ct] = (f32x4){0.f, 0.f, 0.f, 0.f};
#pragma unroll
    for (int ct = 0; ct < 4; ++ct)
#pragma unroll
      for (int kc = 0; kc < 4; ++kc) {
        bf16x8 kf = *reinterpret_cast<const bf16x8*>(&lK[kc * 2048 + (ct * 16 + rl) * 32 + gx8]);
        s[ct] = __builtin_amdgcn_mfma_f32_16x16x32_bf16(qf[kc], kf, s[ct], 0, 0, 0);
      }
    asm volatile("s_waitcnt lgkmcnt(0)" ::: "memory");
    __builtin_amdgcn_sched_barrier(0);
    __builtin_amdgcn_s_barrier();  // all waves done reading lK

    if (t < tmax) stage_K(lK, Kp, b, h, t + 1, w, lane);

    // --- V(t) ready (K(t+1) = newest 4 stay in flight) ---
    if (t < tmax) asm volatile("s_waitcnt vmcnt(4)" ::: "memory");
    else          asm volatile("s_waitcnt vmcnt(0)" ::: "memory");
    __builtin_amdgcn_s_barrier();
    __builtin_amdgcn_sched_barrier(0);

    // --- mask / online softmax ---
    if (t == qt) {
#pragma unroll
      for (int ct = 0; ct < 4; ++ct) {
        int kg = t * 64 + ct * 16 + rl;
#pragma unroll
        for (int j = 0; j < 4; ++j)
          if (kg > qg0 + j) s[ct][j] = -1e30f;
      }
    }
    float mx[4], al[4];
#pragma unroll
    for (int j = 0; j < 4; ++j)
      mx[j] = fmaxf(fmaxf(s[0][j], s[1][j]), fmaxf(s[2][j], s[3][j]));
#pragma unroll
    for (int off = 1; off < 16; off <<= 1)
#pragma unroll
      for (int j = 0; j < 4; ++j) mx[j] = fmaxf(mx[j], __shfl_xor(mx[j], off));
#pragma unroll
    for (int j = 0; j < 4; ++j) {
      float mn = fmaxf(m[j], mx[j]);
      al[j] = __expf(m[j] - mn);
      m[j] = mn;
    }
    float rs[4] = {0.f, 0.f, 0.f, 0.f};
#pragma unroll
    for (int ct = 0; ct < 4; ++ct)
#pragma unroll
      for (int j = 0; j < 4; ++j) {
        float p = __expf(s[ct][j] - m[j]);
        s[ct][j] = p;
        rs[j] += p;
      }
#pragma unroll
    for (int off = 1; off < 16; off <<= 1)
#pragma unroll
      for (int j = 0; j < 4; ++j) rs[j] += __shfl_xor(rs[j], off);
#pragma unroll
    for (int j = 0; j < 4; ++j) l[j] = l[j] * al[j] + rs[j];
#pragma unroll
    for (int dt = 0; dt < 8; ++dt)
#pragma unroll
      for (int j = 0; j < 4; ++j) oacc[dt][j] *= al[j];

    // --- P -> per-wave LDS, then PV ---
#pragma unroll
    for (int ct = 0; ct < 4; ++ct)
#pragma unroll
      for (int j = 0; j < 4; ++j) plds[w][g * 4 + j][ct * 16 + rl] = f2b(s[ct][j]);

    bf16x8 pa[2];
#pragma unroll
    for (int kc2 = 0; kc2 < 2; ++kc2)
      pa[kc2] = *reinterpret_cast<const bf16x8*>(&plds[w][rl][kc2 * 32 + g * 8]);

#pragma unroll
    for (int dt = 0; dt < 8; ++dt)
#pragma unroll
      for (int kc2 = 0; kc2 < 2; ++kc2) {
        bf16x8 vf = *reinterpret_cast<const bf16x8*>(&lV[kc2 * 4096 + (dt * 16 + rl) * 32 + gx8]);
        oacc[dt] = __builtin_amdgcn_mfma_f32_16x16x32_bf16(pa[kc2], vf, oacc[dt], 0, 0, 0);
      }

    asm volatile("s_waitcnt lgkmcnt(0)" ::: "memory");
    __builtin_amdgcn_sched_barrier(0);
    __builtin_amdgcn_s_barrier();  // all waves done reading lV

    if (t < tmax) stage_V(lV, Vt, bh, t + 1, w, lane);
  }

  float inv[4];
#pragma unroll
  for (int j = 0; j < 4; ++j) inv[j] = 1.f / l[j];
#pragma unroll
  for (int dt = 0; dt < 8; ++dt)
#pragma unroll
    for (int j = 0; j < 4; ++j)
      O[(qrow + g * 4 + j) * DIM + h * HDIM + dt * 16 + rl] = f2b(oacc[dt][j] * inv[j]);
}

// ---------------- RMSNorm: fp32 in, fp32 weight; out bf16 or fp32 ----------------
__global__ __launch_bounds__(256) void rmsnorm_to_bf16(const float* __restrict__ X, const float* __restrict__ W,
                                                       u16* __restrict__ O) {
  int row = blockIdx.x, tid = threadIdx.x;
  const float* xr = X + (size_t)row * DIM + tid * 8;
  float4 a = *(const float4*)xr;
  float4 bq = *(const float4*)(xr + 4);
  float v[8] = {a.x, a.y, a.z, a.w, bq.x, bq.y, bq.z, bq.w};
  float ss = 0.f;
#pragma unroll
  for (int j = 0; j < 8; ++j) ss += v[j] * v[j];
#pragma unroll
  for (int off = 32; off; off >>= 1) ss += __shfl_xor(ss, off);
  __shared__ float wss[4];
  int wave = tid >> 6, lane = tid & 63;
  if (lane == 0) wss[wave] = ss;
  __syncthreads();
  float r = rsqrtf((wss[0] + wss[1] + wss[2] + wss[3]) * (1.f / DIM) + 1e-6f);
  float4 wa = *(const float4*)(W + tid * 8);
  float4 wb = *(const float4*)(W + tid * 8 + 4);
  float wv[8] = {wa.x, wa.y, wa.z, wa.w, wb.x, wb.y, wb.z, wb.w};
  uint4 ou;
  ou.x = (u32)f2b(v[0] * r * wv[0]) | ((u32)f2b(v[1] * r * wv[1]) << 16);
  ou.y = (u32)f2b(v[2] * r * wv[2]) | ((u32)f2b(v[3] * r * wv[3]) << 16);
  ou.z = (u32)f2b(v[4] * r * wv[4]) | ((u32)f2b(v[5] * r * wv[5]) << 16);
  ou.w = (u32)f2b(v[6] * r * wv[6]) | ((u32)f2b(v[7] * r * wv[7]) << 16);
  *(uint4*)(O + (size_t)row * DIM + tid * 8) = ou;
}

__global__ __launch_bounds__(256) void rmsnorm_to_f32(const float* __restrict__ X, const float* __restrict__ W,
                                                      float* __restrict__ O) {
  int row = blockIdx.x, tid = threadIdx.x;
  const float* xr = X + (size_t)row * DIM + tid * 8;
  float4 a = *(const float4*)xr;
  float4 bq = *(const float4*)(xr + 4);
  float v[8] = {a.x, a.y, a.z, a.w, bq.x, bq.y, bq.z, bq.w};
  float ss = 0.f;
#pragma unroll
  for (int j = 0; j < 8; ++j) ss += v[j] * v[j];
#pragma unroll
  for (int off = 32; off; off >>= 1) ss += __shfl_xor(ss, off);
  __shared__ float wss[4];
  int wave = tid >> 6, lane = tid & 63;
  if (lane == 0) wss[wave] = ss;
  __syncthreads();
  float r = rsqrtf((wss[0] + wss[1] + wss[2] + wss[3]) * (1.f / DIM) + 1e-6f);
  float4 wa = *(const float4*)(W + tid * 8);
  float4 wb = *(const float4*)(W + tid * 8 + 4);
  float wv[8] = {wa.x, wa.y, wa.z, wa.w, wb.x, wb.y, wb.z, wb.w};
  float4 o0 = {v[0] * r * wv[0], v[1] * r * wv[1], v[2] * r * wv[2], v[3] * r * wv[3]};
  float4 o1 = {v[4] * r * wv[4], v[5] * r * wv[5], v[6] * r * wv[6], v[7] * r * wv[7]};
  *(float4*)(O + (size_t)row * DIM + tid * 8) = o0;
  *(float4*)(O + (size_t)row * DIM + tid * 8 + 4) = o1;
}

// ---------------- launch ----------------
// Workspace layout (u16 units), peak 73.4M u16 = 146.8 MB (proven safe):
//   [0,SZ) xb -> later x1f/x2f (fp32 over [0,2SZ)); [SZ,2SZ) q; [2SZ,3SZ) k;
//   [3SZ,4SZ) v; [4SZ,5SZ) vt; [5SZ,6SZ) hb; [6SZ,+23.07M) weights (time-muxed)
extern "C" void kernel_launch(void* const* d_in, const int* in_sizes, int n_in,
                              void* d_out, int out_size, void* d_ws, size_t ws_size,
                              hipStream_t stream) {
  const float* x     = (const float*)d_in[0];
  const float* wq    = (const float*)d_in[1];
  const float* wk    = (const float*)d_in[2];
  const float* wv    = (const float*)d_in[3];
  const float* wo    = (const float*)d_in[4];
  const float* w_mlp = (const float*)d_in[5];
  const float* v_mlp = (const float*)d_in[6];
  const float* w2    = (const float*)d_in[7];
  const float* n1w   = (const float*)d_in[8];
  const float* n2w   = (const float*)d_in[9];
  const float* fcos  = (const float*)d_in[10];
  const float* fsin  = (const float*)d_in[11];

  u16* ws = (u16*)d_ws;
  const size_t SZ = (size_t)ROWS * DIM;
  const size_t DD = (size_t)DIM * DIM;
  const size_t DH = (size_t)DIM * HIDDEN;

  u16* xb  = ws;
  u16* q   = ws + SZ;
  u16* k   = ws + 2 * SZ;
  u16* v   = ws + 3 * SZ;
  u16* vt  = ws + 4 * SZ;
  u16* hb  = ws + 5 * SZ;
  u16* W   = ws + 6 * SZ;
  u16* wqT = W;
  u16* wkT = W + DD;
  u16* wvT = W + 2 * DD;
  u16* woT = W + 3 * DD;
  u16* wmb = W;
  u16* vmb = W + DH;
  u16* w2b = W;
  float* x1f = (float*)ws;
  float* x2f = (float*)ws;
  u16* ba  = ws + 2 * SZ;

  dim3 blk(256);

  // phase 0: input + attn weight conversion
  cvt_f2b<<<(int)(SZ / 4 / 256), blk, 0, stream>>>(x, xb, (int)SZ);
  dim3 gT(DIM / 32, DIM / 32);
  cvtT<<<gT, blk, 0, stream>>>(wq, wqT, DIM, DIM);
  cvtT<<<gT, blk, 0, stream>>>(wk, wkT, DIM, DIM);
  cvtT<<<gT, blk, 0, stream>>>(wv, wvT, DIM, DIM);
  cvtT<<<gT, blk, 0, stream>>>(wo, woT, DIM, DIM);

  // fused QKV projection (128^2, proven): split store into q,k,v
  dim3 gQKV(3 * DIM / 128, ROWS / 128);  // (48, 32)
  gemm_bt<4><<<gQKV, blk, 0, stream>>>(xb, W, nullptr, q, ROWS, 3 * DIM, DIM);

  cvt_f2b<<<(int)(DH / 4 / 256), blk, 0, stream>>>(w_mlp, wmb, (int)DH);

  rope_kernel<<<(ROWS * NHEAD * 64) / 256, blk, 0, stream>>>(q, k, fcos, fsin);
  vtrans<<<dim3(SEQ / 32, HDIM / 32, BATCH * NHEAD), blk, 0, stream>>>(v, vt);

  // flash attention: 1024 blocks, 3/CU; out -> v buffer
  attn_kernel<<<dim3(SEQ / 64, BATCH * NHEAD), blk, 0, stream>>>(q, k, vt, v);

  // o-proj + fp32 residual x -> x1f
  dim3 gP(DIM / 128, ROWS / 128);
  gemm_bt<1><<<gP, blk, 0, stream>>>(v, woT, x, x1f, ROWS, DIM, DIM);

  cvt_f2b<<<(int)(DH / 4 / 256), blk, 0, stream>>>(v_mlp, vmb, (int)DH);

  rmsnorm_to_bf16<<<ROWS, blk, 0, stream>>>(x1f, n1w, hb);

  // MLP up + gate (128^2, proven)
  dim3 gM1(HIDDEN / 128, ROWS / 128);  // (44, 32)
  gemm_bt<0><<<gM1, blk, 0, stream>>>(hb, wmb, nullptr, ba, ROWS, HIDDEN, DIM);
  gemm_bt<2><<<gM1, blk, 0, stream>>>(hb, vmb, ba, ba, ROWS, HIDDEN, DIM);

  cvt_f2b<<<(int)(DH / 4 / 256), blk, 0, stream>>>(w2, w2b, (int)DH);

  // down-proj + bf16 residual h -> x2f
  gemm_bt<3><<<gP, blk, 0, stream>>>(ba, w2b, hb, x2f, ROWS, DIM, HIDDEN);
  rmsnorm_to_f32<<<ROWS, blk, 0, stream>>>(x2f, n2w, (float*)d_out);
}

// Round 8
// 788.915 us; speedup vs baseline: 1.1002x; 1.0315x over previous
//
#include <hip/hip_runtime.h>

typedef unsigned short u16;
typedef unsigned int u32;
typedef float f32x4 __attribute__((ext_vector_type(4)));
typedef short bf16x8 __attribute__((ext_vector_type(8)));

#define DIM 2048
#define SEQ 2048
#define NHEAD 16
#define HDIM 128
#define BATCH 2
#define HIDDEN 5632
#define ROWS 4096  // BATCH*SEQ

__device__ __forceinline__ float b2f(u16 h) { return __uint_as_float(((u32)h) << 16); }
__device__ __forceinline__ u16 f2b(float f) {
  u32 u = __float_as_uint(f);
  return (u16)((u + 0x7fffu + ((u >> 16) & 1u)) >> 16);
}

// ---------------- fp32 -> bf16 elementwise ----------------
__global__ __launch_bounds__(256) void cvt_f2b(const float* __restrict__ in, u16* __restrict__ out, int n) {
  int i = (blockIdx.x * 256 + threadIdx.x) * 4;
  if (i < n) {
    float4 v = *(const float4*)(in + i);
    u32 p0 = (u32)f2b(v.x) | ((u32)f2b(v.y) << 16);
    u32 p1 = (u32)f2b(v.z) | ((u32)f2b(v.w) << 16);
    *(uint2*)(out + i) = make_uint2(p0, p1);
  }
}

// ---------------- fp32 [R,C] -> bf16 transposed [C,R] ----------------
__global__ __launch_bounds__(256) void cvtT(const float* __restrict__ in, u16* __restrict__ out,
                                            int Rr, int Cc) {
  __shared__ float t[32][33];
  int tx = threadIdx.x & 31, ty = threadIdx.x >> 5;
  int r0 = blockIdx.y * 32, c0 = blockIdx.x * 32;
#pragma unroll
  for (int rr = 0; rr < 4; ++rr)
    t[ty + rr * 8][tx] = in[(size_t)(r0 + ty + rr * 8) * Cc + c0 + tx];
  __syncthreads();
#pragma unroll
  for (int rr = 0; rr < 4; ++rr)
    out[(size_t)(c0 + ty + rr * 8) * Rr + r0 + tx] = f2b(t[tx][ty + rr * 8]);
}

// ================= gemm8p v2: BM=128 x BN=256, BK=64, 8 waves, 8-phase counted-vmcnt =================
// C[M,N] = A[M,K] * Bt[N,K]^T. Grids: (N/256, M/128). LDS 96KB (A 2x16KB, B 2x32KB) -> 1 block/CU.
// m-major XCD chunks: per-XCD B slice <=3MB (L2-resident); A streams via L3.
// Per iter (2 K-steps k0,k1): 8 phases; stages at ph1,2 (B k0+2), ph4 (A k0+2), ph5,6 (B k0+3),
// ph7 (A k0+3). FIFO-derived waits: vmcnt(4)@ph3, vmcnt(6)@ph7 (0 on last iter).
// st_16x32 swizzle on [row][32] panels (64B rows): slot ^= ((row>>3)&1)<<1, applied on the
// pre-swizzled GLOBAL source at staging and on ds_read (verified conflict-free, round 6: 0 conflicts).
// EPI: 0 bf16; 1 fp32 C=acc+fp32 R; 2 bf16 C=silu(R)*acc; 3 fp32 C=acc+bf16 R; 4 QKV split
template <int EPI>
__global__ __launch_bounds__(512, 2) void gemm8p(const u16* __restrict__ A, const u16* __restrict__ Bt,
                                                 const void* R_, void* C_, int M, int N, int K) {
  __shared__ u16 LA[2][8192];       // [par][kk*4096 + row*32 + elem]
  __shared__ u16 LB[2][2][8192];    // [par][hf][kk*4096 + row*32 + elem]
  const int tid = threadIdx.x;
  const int lane = tid & 63, wid = tid >> 6;
  const int wr = wid >> 2, wc = wid & 3;      // 2M x 4N waves
  const int rl = lane & 15, g = lane >> 4;
  const int s2 = ((rl >> 3) & 1) << 1;        // read-side swizzle
  const int gx = gridDim.x, gy = gridDim.y;
  const int id = blockIdx.y * gx + blockIdx.x;
  const int cpx = (gx * gy) >> 3;
  const int sw = (id & 7) * cpx + (id >> 3);
  const int m0 = (sw % gy) * 128, n0 = (sw / gy) * 256;  // m-major within XCD chunk
  const int nk = K >> 6;

  const int srow = tid >> 2;                              // 0..127
  const int sslot = (tid & 3) ^ (((tid >> 5) & 1) << 1);  // pre-swizzled global slot

  auto SHA = [&](int ks) {
    const u16* gp = A + (size_t)(m0 + srow) * K + ks * 64 + sslot * 8;
#pragma unroll
    for (int kk = 0; kk < 2; ++kk)
      __builtin_amdgcn_global_load_lds(
          (const __attribute__((address_space(1))) void*)(gp + kk * 32),
          (__attribute__((address_space(3))) void*)&LA[ks & 1][kk * 4096 + wid * 512], 16, 0, 0);
  };
  auto SHB = [&](int ks, int hf) {
    const u16* gp = Bt + (size_t)(n0 + hf * 128 + srow) * K + ks * 64 + sslot * 8;
#pragma unroll
    for (int kk = 0; kk < 2; ++kk)
      __builtin_amdgcn_global_load_lds(
          (const __attribute__((address_space(1))) void*)(gp + kk * 32),
          (__attribute__((address_space(3))) void*)&LB[ks & 1][hf][kk * 4096 + wid * 512], 16, 0, 0);
  };

  f32x4 acc[4][4];
#pragma unroll
  for (int a = 0; a < 4; ++a)
#pragma unroll
    for (int b = 0; b < 4; ++b) acc[a][b] = (f32x4){0.f, 0.f, 0.f, 0.f};
  bf16x8 bf[4][2];

#define PH8(kst, q, STAGE, VMN)                                                                 \
  do {                                                                                          \
    const int c_ = (kst) & 1;                                                                   \
    if ((q) == 0) {                                                                             \
      _Pragma("unroll") for (int ni = 0; ni < 4; ++ni)                                          \
          _Pragma("unroll") for (int kk = 0; kk < 2; ++kk)                                      \
              bf[ni][kk] = *(const bf16x8*)&LB[c_][wc >> 1]                                     \
                  [kk * 4096 + ((wc & 1) * 64 + ni * 16 + rl) * 32 + (g ^ s2) * 8];             \
    }                                                                                           \
    bf16x8 af[2];                                                                               \
    _Pragma("unroll") for (int kk = 0; kk < 2; ++kk)                                            \
        af[kk] = *(const bf16x8*)&LA[c_]                                                        \
            [kk * 4096 + (wr * 64 + (q) * 16 + rl) * 32 + (g ^ s2) * 8];                        \
    STAGE;                                                                                      \
    __builtin_amdgcn_s_barrier();                                                               \
    asm volatile("s_waitcnt lgkmcnt(0)" ::: "memory");                                          \
    __builtin_amdgcn_sched_barrier(0);                                                          \
    __builtin_amdgcn_s_setprio(1);                                                              \
    _Pragma("unroll") for (int kk = 0; kk < 2; ++kk)                                            \
        _Pragma("unroll") for (int ni = 0; ni < 4; ++ni)                                        \
            acc[(q)][ni] = __builtin_amdgcn_mfma_f32_16x16x32_bf16(                             \
                af[kk], bf[ni][kk], acc[(q)][ni], 0, 0, 0);                                     \
    __builtin_amdgcn_s_setprio(0);                                                              \
    if ((VMN) == 4) asm volatile("s_waitcnt vmcnt(4)" ::: "memory");                            \
    else if ((VMN) == 6) asm volatile("s_waitcnt vmcnt(6)" ::: "memory");                       \
    else if ((VMN) == 0) asm volatile("s_waitcnt vmcnt(0)" ::: "memory");                       \
    __builtin_amdgcn_s_barrier();                                                               \
  } while (0)

  // prologue (FIFO order = steady state: B(k) before A(k)): B(0), A(0), B(1), A(1)
  SHB(0, 0); SHB(0, 1); SHA(0); SHB(1, 0); SHB(1, 1); SHA(1);
  asm volatile("s_waitcnt vmcnt(6)" ::: "memory");  // oldest 6 = B(0)+A(0)
  __builtin_amdgcn_s_barrier();

  const int nk2 = nk >> 1;
  for (int i = 0; i < nk2; ++i) {
    const int k0 = 2 * i, k1 = 2 * i + 1;
    const bool st = (k0 + 2) < nk;
    PH8(k0, 0, , -1);
    PH8(k0, 1, if (st) SHB(k0 + 2, 0), -1);
    PH8(k0, 2, if (st) SHB(k0 + 2, 1), -1);
    PH8(k0, 3, , st ? 4 : 0);
    PH8(k1, 0, if (st) SHA(k0 + 2), -1);
    PH8(k1, 1, if (st) SHB(k0 + 3, 0), -1);
    PH8(k1, 2, if (st) SHB(k0 + 3, 1), -1);
    PH8(k1, 3, if (st) SHA(k0 + 3), st ? 6 : 0);
  }
#undef PH8

#pragma unroll
  for (int mi = 0; mi < 4; ++mi)
#pragma unroll
    for (int ni = 0; ni < 4; ++ni)
#pragma unroll
      for (int j = 0; j < 4; ++j) {
        size_t row = m0 + wr * 64 + mi * 16 + g * 4 + j;
        size_t col = n0 + wc * 64 + ni * 16 + rl;
        size_t idx = row * N + col;
        float v = acc[mi][ni][j];
        if (EPI == 0) {
          ((u16*)C_)[idx] = f2b(v);
        } else if (EPI == 1) {
          ((float*)C_)[idx] = v + ((const float*)R_)[idx];
        } else if (EPI == 2) {
          float av = b2f(((const u16*)R_)[idx]);
          ((u16*)C_)[idx] = f2b(v * av / (1.f + __expf(-av)));
        } else if (EPI == 3) {
          ((float*)C_)[idx] = v + b2f(((const u16*)R_)[idx]);
        } else {  // EPI == 4: QKV split store
          size_t di = (col >> 11) * (size_t)(ROWS * (size_t)DIM) + row * DIM + (col & (DIM - 1));
          ((u16*)C_)[di] = f2b(v);
        }
      }
}

// ---------------- V [B,S,H,D] bf16 -> Vt [B,H,D,S] bf16 ----------------
__global__ __launch_bounds__(256) void vtrans(const u16* __restrict__ V, u16* __restrict__ Vt) {
  __shared__ u16 t[32][33];
  int tx = threadIdx.x & 31, ty = threadIdx.x >> 5;
  int s0 = blockIdx.x * 32, d0 = blockIdx.y * 32;
  int bh = blockIdx.z, b = bh >> 4, h = bh & 15;
#pragma unroll
  for (int rr = 0; rr < 4; ++rr)
    t[ty + rr * 8][tx] = V[(size_t)(b * SEQ + s0 + ty + rr * 8) * DIM + h * HDIM + d0 + tx];
  __syncthreads();
#pragma unroll
  for (int rr = 0; rr < 4; ++rr)
    Vt[(size_t)(bh * HDIM + d0 + ty + rr * 8) * SEQ + s0 + tx] = t[tx][ty + rr * 8];
}

// ---------------- RoPE in-place on bf16 q,k; fp32 cos/sin; q scaled 1/sqrt(HDIM) ----------------
__global__ __launch_bounds__(256) void rope_kernel(u16* __restrict__ Q, u16* __restrict__ Kv,
                                                   const float* __restrict__ Cz, const float* __restrict__ Sz) {
  int t = blockIdx.x * 256 + threadIdx.x;
  int i = t & 63;
  int hh = (t >> 6) & 15;
  int row = t >> 10;
  int s = row & (SEQ - 1);
  float c = Cz[s * 64 + i], sn = Sz[s * 64 + i];
  size_t off = (size_t)row * DIM + hh * HDIM + 2 * i;
  const float sc = 0.08838834764831843f;

  u32 qp = *(const u32*)(Q + off);
  float q0 = b2f((u16)qp), q1 = b2f((u16)(qp >> 16));
  float o0 = (q0 * c - q1 * sn) * sc, o1 = (q0 * sn + q1 * c) * sc;
  *(u32*)(Q + off) = (u32)f2b(o0) | ((u32)f2b(o1) << 16);

  u32 kp = *(const u32*)(Kv + off);
  float k0 = b2f((u16)kp), k1 = b2f((u16)(kp >> 16));
  o0 = k0 * c - k1 * sn; o1 = k0 * sn + k1 * c;
  *(u32*)(Kv + off) = (u32)f2b(o0) | ((u32)f2b(o1) << 16);
}

// ---------------- flash attention (causal), unchanged from round 7 ----------------
__device__ __forceinline__ void stage_K(u16* lk, const u16* __restrict__ Kg,
                                        int b, int h, int t, int w, int lane) {
  const int r4 = lane >> 2;
  const int gsw = (lane & 3) ^ (r4 & 3);
#pragma unroll
  for (int j = 0; j < 4; ++j) {
    const u16* gp = Kg + (size_t)(b * SEQ + t * 64 + j * 16 + r4) * DIM +
                    h * HDIM + w * 32 + gsw * 8;
    __builtin_amdgcn_global_load_lds((const __attribute__((address_space(1))) void*)gp,
                                     (__attribute__((address_space(3))) void*)(lk + w * 2048 + j * 512),
                                     16, 0, 0);
  }
}

__device__ __forceinline__ void stage_V(u16* lv, const u16* __restrict__ Vg,
                                        int bh, int t, int w, int lane) {
  const int r4 = lane >> 2;
  const int gsw = (lane & 3) ^ (r4 & 3);
#pragma unroll
  for (int j = 0; j < 4; ++j) {
    int id = w * 4 + j, kc2 = id >> 3, rg = id & 7;
    const u16* gp = Vg + (size_t)(bh * HDIM + rg * 16 + r4) * SEQ +
                    t * 64 + kc2 * 32 + gsw * 8;
    __builtin_amdgcn_global_load_lds((const __attribute__((address_space(1))) void*)gp,
                                     (__attribute__((address_space(3))) void*)(lv + kc2 * 4096 + rg * 512),
                                     16, 0, 0);
  }
}

__global__ __launch_bounds__(256, 3) void attn_kernel(const u16* __restrict__ Q, const u16* __restrict__ Kp,
                                                      const u16* __restrict__ Vt, u16* __restrict__ O) {
  const int lane = threadIdx.x & 63;
  const int w = threadIdx.x >> 6;
  const int id = blockIdx.y * 32 + blockIdx.x;
  const int sw = (id & 7) * 128 + (id >> 3);
  const int qt = sw & 31;
  const int bh = sw >> 5;
  const int b = bh >> 4, h = bh & 15;
  const int rl = lane & 15, g = lane >> 4;
  const int gx8 = (g ^ (rl & 3)) * 8;

  __shared__ u16 lK[8192];
  __shared__ u16 lV[8192];
  __shared__ u16 plds[4][16][72];

  const size_t qrow = (size_t)b * SEQ + qt * 64 + w * 16;
  bf16x8 qf[4];
#pragma unroll
  for (int kc = 0; kc < 4; ++kc)
    qf[kc] = *reinterpret_cast<const bf16x8*>(Q + (qrow + rl) * DIM + h * HDIM + kc * 32 + g * 8);

  float m[4], l[4];
  f32x4 oacc[8];
#pragma unroll
  for (int j = 0; j < 4; ++j) { m[j] = -1e30f; l[j] = 0.f; }
#pragma unroll
  for (int dt = 0; dt < 8; ++dt) oacc[dt] = (f32x4){0.f, 0.f, 0.f, 0.f};

  const int qg0 = qt * 64 + w * 16 + g * 4;
  const int tmax = qt;

  stage_K(lK, Kp, b, h, 0, w, lane);
  stage_V(lV, Vt, bh, 0, w, lane);

  for (int t = 0; t <= tmax; ++t) {
    asm volatile("s_waitcnt vmcnt(4)" ::: "memory");
    __builtin_amdgcn_s_barrier();
    __builtin_amdgcn_sched_barrier(0);

    f32x4 s[4];
#pragma unroll
    for (int ct = 0; ct < 4; ++ct) s[ct] = (f32x4){0.f, 0.f, 0.f, 0.f};
#pragma unroll
    for (int ct = 0; ct < 4; ++ct)
#pragma unroll
      for (int kc = 0; kc < 4; ++kc) {
        bf16x8 kf = *reinterpret_cast<const bf16x8*>(&lK[kc * 2048 + (ct * 16 + rl) * 32 + gx8]);
        s[ct] = __builtin_amdgcn_mfma_f32_16x16x32_bf16(qf[kc], kf, s[ct], 0, 0, 0);
      }
    asm volatile("s_waitcnt lgkmcnt(0)" ::: "memory");
    __builtin_amdgcn_sched_barrier(0);
    __builtin_amdgcn_s_barrier();

    if (t < tmax) stage_K(lK, Kp, b, h, t + 1, w, lane);

    if (t < tmax) asm volatile("s_waitcnt vmcnt(4)" ::: "memory");
    else          asm volatile("s_waitcnt vmcnt(0)" ::: "memory");
    __builtin_amdgcn_s_barrier();
    __builtin_amdgcn_sched_barrier(0);

    if (t == qt) {
#pragma unroll
      for (int ct = 0; ct < 4; ++ct) {
        int kg = t * 64 + ct * 16 + rl;
#pragma unroll
        for (int j = 0; j < 4; ++j)
          if (kg > qg0 + j) s[ct][j] = -1e30f;
      }
    }
    float mx[4], al[4];
#pragma unroll
    for (int j = 0; j < 4; ++j)
      mx[j] = fmaxf(fmaxf(s[0][j], s[1][j]), fmaxf(s[2][j], s[3][j]));
#pragma unroll
    for (int off = 1; off < 16; off <<= 1)
#pragma unroll
      for (int j = 0; j < 4; ++j) mx[j] = fmaxf(mx[j], __shfl_xor(mx[j], off));
#pragma unroll
    for (int j = 0; j < 4; ++j) {
      float mn = fmaxf(m[j], mx[j]);
      al[j] = __expf(m[j] - mn);
      m[j] = mn;
    }
    float rs[4] = {0.f, 0.f, 0.f, 0.f};
#pragma unroll
    for (int ct = 0; ct < 4; ++ct)
#pragma unroll
      for (int j = 0; j < 4; ++j) {
        float p = __expf(s[ct][j] - m[j]);
        s[ct][j] = p;
        rs[j] += p;
      }
#pragma unroll
    for (int off = 1; off < 16; off <<= 1)
#pragma unroll
      for (int j = 0; j < 4; ++j) rs[j] += __shfl_xor(rs[j], off);
#pragma unroll
    for (int j = 0; j < 4; ++j) l[j] = l[j] * al[j] + rs[j];
#pragma unroll
    for (int dt = 0; dt < 8; ++dt)
#pragma unroll
      for (int j = 0; j < 4; ++j) oacc[dt][j] *= al[j];

#pragma unroll
    for (int ct = 0; ct < 4; ++ct)
#pragma unroll
      for (int j = 0; j < 4; ++j) plds[w][g * 4 + j][ct * 16 + rl] = f2b(s[ct][j]);

    bf16x8 pa[2];
#pragma unroll
    for (int kc2 = 0; kc2 < 2; ++kc2)
      pa[kc2] = *reinterpret_cast<const bf16x8*>(&plds[w][rl][kc2 * 32 + g * 8]);

#pragma unroll
    for (int dt = 0; dt < 8; ++dt)
#pragma unroll
      for (int kc2 = 0; kc2 < 2; ++kc2) {
        bf16x8 vf = *reinterpret_cast<const bf16x8*>(&lV[kc2 * 4096 + (dt * 16 + rl) * 32 + gx8]);
        oacc[dt] = __builtin_amdgcn_mfma_f32_16x16x32_bf16(pa[kc2], vf, oacc[dt], 0, 0, 0);
      }

    asm volatile("s_waitcnt lgkmcnt(0)" ::: "memory");
    __builtin_amdgcn_sched_barrier(0);
    __builtin_amdgcn_s_barrier();

    if (t < tmax) stage_V(lV, Vt, bh, t + 1, w, lane);
  }

  float inv[4];
#pragma unroll
  for (int j = 0; j < 4; ++j) inv[j] = 1.f / l[j];
#pragma unroll
  for (int dt = 0; dt < 8; ++dt)
#pragma unroll
    for (int j = 0; j < 4; ++j)
      O[(qrow + g * 4 + j) * DIM + h * HDIM + dt * 16 + rl] = f2b(oacc[dt][j] * inv[j]);
}

// ---------------- RMSNorm: fp32 in, fp32 weight; out bf16 or fp32 ----------------
__global__ __launch_bounds__(256) void rmsnorm_to_bf16(const float* __restrict__ X, const float* __restrict__ W,
                                                       u16* __restrict__ O) {
  int row = blockIdx.x, tid = threadIdx.x;
  const float* xr = X + (size_t)row * DIM + tid * 8;
  float4 a = *(const float4*)xr;
  float4 bq = *(const float4*)(xr + 4);
  float v[8] = {a.x, a.y, a.z, a.w, bq.x, bq.y, bq.z, bq.w};
  float ss = 0.f;
#pragma unroll
  for (int j = 0; j < 8; ++j) ss += v[j] * v[j];
#pragma unroll
  for (int off = 32; off; off >>= 1) ss += __shfl_xor(ss, off);
  __shared__ float wss[4];
  int wave = tid >> 6, lane = tid & 63;
  if (lane == 0) wss[wave] = ss;
  __syncthreads();
  float r = rsqrtf((wss[0] + wss[1] + wss[2] + wss[3]) * (1.f / DIM) + 1e-6f);
  float4 wa = *(const float4*)(W + tid * 8);
  float4 wb = *(const float4*)(W + tid * 8 + 4);
  float wv[8] = {wa.x, wa.y, wa.z, wa.w, wb.x, wb.y, wb.z, wb.w};
  uint4 ou;
  ou.x = (u32)f2b(v[0] * r * wv[0]) | ((u32)f2b(v[1] * r * wv[1]) << 16);
  ou.y = (u32)f2b(v[2] * r * wv[2]) | ((u32)f2b(v[3] * r * wv[3]) << 16);
  ou.z = (u32)f2b(v[4] * r * wv[4]) | ((u32)f2b(v[5] * r * wv[5]) << 16);
  ou.w = (u32)f2b(v[6] * r * wv[6]) | ((u32)f2b(v[7] * r * wv[7]) << 16);
  *(uint4*)(O + (size_t)row * DIM + tid * 8) = ou;
}

__global__ __launch_bounds__(256) void rmsnorm_to_f32(const float* __restrict__ X, const float* __restrict__ W,
                                                      float* __restrict__ O) {
  int row = blockIdx.x, tid = threadIdx.x;
  const float* xr = X + (size_t)row * DIM + tid * 8;
  float4 a = *(const float4*)xr;
  float4 bq = *(const float4*)(xr + 4);
  float v[8] = {a.x, a.y, a.z, a.w, bq.x, bq.y, bq.z, bq.w};
  float ss = 0.f;
#pragma unroll
  for (int j = 0; j < 8; ++j) ss += v[j] * v[j];
#pragma unroll
  for (int off = 32; off; off >>= 1) ss += __shfl_xor(ss, off);
  __shared__ float wss[4];
  int wave = tid >> 6, lane = tid & 63;
  if (lane == 0) wss[wave] = ss;
  __syncthreads();
  float r = rsqrtf((wss[0] + wss[1] + wss[2] + wss[3]) * (1.f / DIM) + 1e-6f);
  float4 wa = *(const float4*)(W + tid * 8);
  float4 wb = *(const float4*)(W + tid * 8 + 4);
  float wv[8] = {wa.x, wa.y, wa.z, wa.w, wb.x, wb.y, wb.z, wb.w};
  float4 o0 = {v[0] * r * wv[0], v[1] * r * wv[1], v[2] * r * wv[2], v[3] * r * wv[3]};
  float4 o1 = {v[4] * r * wv[4], v[5] * r * wv[5], v[6] * r * wv[6], v[7] * r * wv[7]};
  *(float4*)(O + (size_t)row * DIM + tid * 8) = o0;
  *(float4*)(O + (size_t)row * DIM + tid * 8 + 4) = o1;
}

// ---------------- launch ----------------
// Workspace layout (u16 units), peak 73.4M u16 = 146.8 MB (proven safe):
//   [0,SZ) xb -> later x1f/x2f (fp32 over [0,2SZ)); [SZ,2SZ) q; [2SZ,3SZ) k;
//   [3SZ,4SZ) v; [4SZ,5SZ) vt; [5SZ,6SZ) hb; [6SZ,+23.07M) weights (time-muxed)
extern "C" void kernel_launch(void* const* d_in, const int* in_sizes, int n_in,
                              void* d_out, int out_size, void* d_ws, size_t ws_size,
                              hipStream_t stream) {
  const float* x     = (const float*)d_in[0];
  const float* wq    = (const float*)d_in[1];
  const float* wk    = (const float*)d_in[2];
  const float* wv    = (const float*)d_in[3];
  const float* wo    = (const float*)d_in[4];
  const float* w_mlp = (const float*)d_in[5];
  const float* v_mlp = (const float*)d_in[6];
  const float* w2    = (const float*)d_in[7];
  const float* n1w   = (const float*)d_in[8];
  const float* n2w   = (const float*)d_in[9];
  const float* fcos  = (const float*)d_in[10];
  const float* fsin  = (const float*)d_in[11];

  u16* ws = (u16*)d_ws;
  const size_t SZ = (size_t)ROWS * DIM;
  const size_t DD = (size_t)DIM * DIM;
  const size_t DH = (size_t)DIM * HIDDEN;

  u16* xb  = ws;
  u16* q   = ws + SZ;
  u16* k   = ws + 2 * SZ;
  u16* v   = ws + 3 * SZ;
  u16* vt  = ws + 4 * SZ;
  u16* hb  = ws + 5 * SZ;
  u16* W   = ws + 6 * SZ;
  u16* wqT = W;
  u16* wkT = W + DD;
  u16* wvT = W + 2 * DD;
  u16* woT = W + 3 * DD;
  u16* wmb = W;
  u16* vmb = W + DH;
  u16* w2b = W;
  float* x1f = (float*)ws;
  float* x2f = (float*)ws;
  u16* ba  = ws + 2 * SZ;

  dim3 blk(256);
  dim3 blk8(512);

  // phase 0: input + attn weight conversion
  cvt_f2b<<<(int)(SZ / 4 / 256), blk, 0, stream>>>(x, xb, (int)SZ);
  dim3 gT(DIM / 32, DIM / 32);
  cvtT<<<gT, blk, 0, stream>>>(wq, wqT, DIM, DIM);
  cvtT<<<gT, blk, 0, stream>>>(wk, wkT, DIM, DIM);
  cvtT<<<gT, blk, 0, stream>>>(wv, wvT, DIM, DIM);
  cvtT<<<gT, blk, 0, stream>>>(wo, woT, DIM, DIM);

  // fused QKV projection: split store into q,k,v  (grid 24x32 = 768 = 3.0 rounds)
  dim3 gQKV(3 * DIM / 256, ROWS / 128);
  gemm8p<4><<<gQKV, blk8, 0, stream>>>(xb, W, nullptr, q, ROWS, 3 * DIM, DIM);

  cvt_f2b<<<(int)(DH / 4 / 256), blk, 0, stream>>>(w_mlp, wmb, (int)DH);

  rope_kernel<<<(ROWS * NHEAD * 64) / 256, blk, 0, stream>>>(q, k, fcos, fsin);
  vtrans<<<dim3(SEQ / 32, HDIM / 32, BATCH * NHEAD), blk, 0, stream>>>(v, vt);

  // flash attention: 1024 blocks, 3/CU; out -> v buffer
  attn_kernel<<<dim3(SEQ / 64, BATCH * NHEAD), blk, 0, stream>>>(q, k, vt, v);

  // o-proj + fp32 residual x -> x1f  (grid 8x32 = 256 = 1.0 round)
  dim3 gP(DIM / 256, ROWS / 128);
  gemm8p<1><<<gP, blk8, 0, stream>>>(v, woT, x, x1f, ROWS, DIM, DIM);

  cvt_f2b<<<(int)(DH / 4 / 256), blk, 0, stream>>>(v_mlp, vmb, (int)DH);

  rmsnorm_to_bf16<<<ROWS, blk, 0, stream>>>(x1f, n1w, hb);

  // MLP up + gate  (grid 22x32 = 704)
  dim3 gM(HIDDEN / 256, ROWS / 128);
  gemm8p<0><<<gM, blk8, 0, stream>>>(hb, wmb, nullptr, ba, ROWS, HIDDEN, DIM);
  gemm8p<2><<<gM, blk8, 0, stream>>>(hb, vmb, ba, ba, ROWS, HIDDEN, DIM);

  cvt_f2b<<<(int)(DH / 4 / 256), blk, 0, stream>>>(w2, w2b, (int)DH);

  // down-proj + bf16 residual h -> x2f  (grid 8x32 = 256, K=5632 deep pipeline)
  gemm8p<3><<<gP, blk8, 0, stream>>>(ba, w2b, hb, x2f, ROWS, DIM, HIDDEN);
  rmsnorm_to_f32<<<ROWS, blk, 0, stream>>>(x2f, n2w, (float*)d_out);
}